// Round 7
// baseline (229.531 us; speedup 1.0000x reference)
//
#include <hip/hip_runtime.h>

constexpr int N_NODES = 100000;
constexpr int N_EDGES = 1600000;
constexpr int D = 32;
constexpr int SCAN_B = 256;
constexpr int NB = (N_NODES + SCAN_B - 1) / SCAN_B;   // 391 scan blocks

__device__ inline unsigned short f2bf(float f) {
    unsigned u = __float_as_uint(f);
    u += 0x7FFFu + ((u >> 16) & 1u);      // round-to-nearest-even
    return (unsigned short)(u >> 16);
}
__device__ inline float bf2f(unsigned short h) {
    return __uint_as_float(((unsigned)h) << 16);
}

// ---------------- primary path (needs ~111 MB workspace) ----------------

// P0: node_inputs f32 -> bf16 rows (64 B/row: one cache line per random read).
__global__ __launch_bounds__(256) void conv_kernel(const float4* __restrict__ in4,
                                                   ushort4* __restrict__ out4) {
    int i = blockIdx.x * 256 + threadIdx.x;            // 800000 exact
    float4 v = in4[i];
    out4[i] = make_ushort4(f2bf(v.x), f2bf(v.y), f2bf(v.z), f2bf(v.w));
}

// P1: degree histogram (int atomics into L2-resident 400 KB).
__global__ __launch_bounds__(256) void deg_hist(const int4* __restrict__ dst4,
                                                int* __restrict__ cnt) {
    int i = blockIdx.x * 256 + threadIdx.x;
    if (i < N_EDGES / 4) {
        int4 d = dst4[i];
        atomicAdd(&cnt[d.x], 1);
        atomicAdd(&cnt[d.y], 1);
        atomicAdd(&cnt[d.z], 1);
        atomicAdd(&cnt[d.w], 1);
    }
}

__device__ inline int wave_incl_scan(int v, int lane) {
    #pragma unroll
    for (int d = 1; d < 64; d <<= 1) {
        int u = __shfl_up(v, d, 64);
        if (lane >= d) v += u;
    }
    return v;
}

// P2a/b/c: device-wide exclusive scan -> offcnt (int2) + cur.
__global__ __launch_bounds__(SCAN_B) void scan_a(const int* __restrict__ cnt,
                                                 int* __restrict__ bsum) {
    __shared__ int ws[SCAN_B / 64];
    int i = blockIdx.x * SCAN_B + threadIdx.x;
    int v = (i < N_NODES) ? cnt[i] : 0;
    #pragma unroll
    for (int d = 32; d >= 1; d >>= 1) v += __shfl_down(v, d, 64);
    if ((threadIdx.x & 63) == 0) ws[threadIdx.x >> 6] = v;
    __syncthreads();
    if (threadIdx.x == 0) bsum[blockIdx.x] = ws[0] + ws[1] + ws[2] + ws[3];
}

__global__ __launch_bounds__(512) void scan_b(const int* __restrict__ bsum,
                                              int* __restrict__ boff) {
    __shared__ int part[512];
    const int t = threadIdx.x;
    int v = (t < NB) ? bsum[t] : 0;
    part[t] = v;
    __syncthreads();
    for (int d = 1; d < 512; d <<= 1) {
        int u = (t >= d) ? part[t - d] : 0;
        __syncthreads();
        part[t] += u;
        __syncthreads();
    }
    if (t < NB) boff[t] = part[t] - v;
}

__global__ __launch_bounds__(SCAN_B) void scan_c(const int* __restrict__ cnt,
                                                 const int* __restrict__ boff,
                                                 int2* __restrict__ offcnt,
                                                 int* __restrict__ cur) {
    __shared__ int wsum[SCAN_B / 64];
    const int i = blockIdx.x * SCAN_B + threadIdx.x;
    const int lane = threadIdx.x & 63;
    const int w = threadIdx.x >> 6;
    int v = (i < N_NODES) ? cnt[i] : 0;
    int incl = wave_incl_scan(v, lane);
    if (lane == 63) wsum[w] = incl;
    __syncthreads();
    int wo = 0;
    for (int k = 0; k < w; ++k) wo += wsum[k];
    const int excl = incl - v + wo + boff[blockIdx.x];
    if (i < N_NODES) {
        offcnt[i] = make_int2(excl, v);
        cur[i] = excl;
    }
}

// P3: stream edges sequentially; 8 lanes per edge (float4/lane = 128 B row);
// claim CSR slot via one int atomic; write 64 B bf16 msg row (single owner).
__global__ __launch_bounds__(256) void mat_kernel(
    const float4* __restrict__ edge4, const ushort4* __restrict__ nodeb4,
    const int* __restrict__ src, const int* __restrict__ dst,
    int* __restrict__ cur, ushort4* __restrict__ msg4)
{
    const int l = threadIdx.x & 63;        // lane in wave
    const int wv = threadIdx.x >> 6;       // wave in block (0..3)
    const int sub = l >> 3;                // edge slot in wave (0..7)
    const int q = l & 7;                   // quarter-row piece (4 elems)

    for (int base = blockIdx.x * 32; base < N_EDGES; base += gridDim.x * 32) {
        const int e = base + wv * 8 + sub;
        const float4 ev = edge4[(long long)e * 8 + q];     // coalesced stream
        const int s = src[e];
        const int d = dst[e];
        const ushort4 nb = nodeb4[(long long)s * 8 + q];   // 64 B random, L2/L3
        const float m0 = fmaxf(ev.x + bf2f(nb.x), 0.0f);
        const float m1 = fmaxf(ev.y + bf2f(nb.y), 0.0f);
        const float m2 = fmaxf(ev.z + bf2f(nb.z), 0.0f);
        const float m3 = fmaxf(ev.w + bf2f(nb.w), 0.0f);
        int p;
        if (q == 0) p = atomicAdd(&cur[d], 1);
        p = __shfl(p, l & ~7, 64);                         // broadcast slot
        msg4[(long long)p * 8 + q] =
            make_ushort4(f2bf(m0), f2bf(m1), f2bf(m2), f2bf(m3));
    }
}

// P4: per-node sequential reduce of contiguous bf16 msg rows + eps + linear.
__global__ __launch_bounds__(256) void reduce_kernel(
    const float* __restrict__ node, const unsigned short* __restrict__ msg,
    const int2* __restrict__ offcnt,
    const float* __restrict__ W, const float* __restrict__ bvec,
    const float* __restrict__ eps, float* __restrict__ out)
{
    __shared__ float Ws[D][D + 1];
    __shared__ float bs[D];
    const int t = threadIdx.x;
    for (int i = t; i < D * D; i += 256) Ws[i >> 5][i & 31] = W[i];
    if (t < D) bs[t] = bvec[t];
    __syncthreads();

    const int g = t >> 5;
    const int o = t & 31;
    const int nodeid = blockIdx.x * 8 + g;                 // 12500*8 exact

    const int2 oc = offcnt[nodeid];
    const int start = oc.x;
    const int n = oc.y;
    float acc = 0.0f;
    for (int c = 0; c < n; c += 8) {
        unsigned short us[8];
        #pragma unroll
        for (int u = 0; u < 8; ++u) {
            const int j = c + u;
            const int jj = (j < n) ? j : (n - 1);          // clamp (n>=1 here)
            us[u] = msg[(long long)(start + jj) * D + o];
        }
        #pragma unroll
        for (int u = 0; u < 8; ++u)
            if (c + u < n) acc += bf2f(us[u]);
    }

    const float scale = 1.0f + eps[0];
    const float h = scale * node[(long long)nodeid * D + o] + acc;

    float r = bs[o];
    #pragma unroll
    for (int k = 0; k < D; ++k) r += __shfl(h, k, 32) * Ws[o][k];
    out[(long long)nodeid * D + o] = r;
}

// ---------------- fallback path (R6, ~7.3 MB workspace) ----------------

constexpr int F_NPB = 256;
constexpr int F_NBUK = (N_NODES + F_NPB - 1) / F_NPB;
constexpr int F_NCHUNK = 64;
constexpr int F_EPC = N_EDGES / F_NCHUNK;
constexpr int F_MAXPT = 32;

__global__ __launch_bounds__(256) void f_hist(const int4* __restrict__ dst4,
                                              int* __restrict__ bgcnt) {
    __shared__ int cnt_s[512];
    const int k = blockIdx.x, t = threadIdx.x;
    cnt_s[t] = 0; cnt_s[t + 256] = 0;
    __syncthreads();
    const int base4 = k * (F_EPC / 4);
    for (int i = t; i < F_EPC / 4; i += 256) {
        int4 d = dst4[base4 + i];
        atomicAdd(&cnt_s[d.x >> 8], 1);
        atomicAdd(&cnt_s[d.y >> 8], 1);
        atomicAdd(&cnt_s[d.z >> 8], 1);
        atomicAdd(&cnt_s[d.w >> 8], 1);
    }
    __syncthreads();
    for (int b = t; b < F_NBUK; b += 256) bgcnt[b * F_NCHUNK + k] = cnt_s[b];
}

__global__ __launch_bounds__(512) void f_offsets(const int* __restrict__ bgcnt,
                                                 int* __restrict__ gstart,
                                                 int* __restrict__ boff) {
    __shared__ int part[512];
    const int t = threadIdx.x;
    int tot = 0;
    if (t < F_NBUK) {
        int run = 0;
        for (int k = 0; k < F_NCHUNK; ++k) {
            gstart[t * F_NCHUNK + k] = run;
            run += bgcnt[t * F_NCHUNK + k];
        }
        tot = run;
    }
    part[t] = tot;
    __syncthreads();
    for (int d = 1; d < 512; d <<= 1) {
        int u = (t >= d) ? part[t - d] : 0;
        __syncthreads();
        part[t] += u;
        __syncthreads();
    }
    const int my_off = part[t] - tot;
    if (t < F_NBUK) {
        boff[t] = my_off;
        for (int k = 0; k < F_NCHUNK; ++k) gstart[t * F_NCHUNK + k] += my_off;
    }
}

__global__ __launch_bounds__(256) void f_scatter(const int4* __restrict__ dst4,
                                                 const int* __restrict__ gstart,
                                                 int* __restrict__ records) {
    __shared__ int cur_s[512];
    const int k = blockIdx.x, t = threadIdx.x;
    for (int b = t; b < 512; b += 256)
        cur_s[b] = (b < F_NBUK) ? gstart[b * F_NCHUNK + k] : 0;
    __syncthreads();
    const int base4 = k * (F_EPC / 4);
    for (int i = t; i < F_EPC / 4; i += 256) {
        int4 d = dst4[base4 + i];
        const int e = (base4 + i) * 4;
        int p;
        p = atomicAdd(&cur_s[d.x >> 8], 1); records[p] = e       | ((d.x & 255) << 21);
        p = atomicAdd(&cur_s[d.y >> 8], 1); records[p] = (e + 1) | ((d.y & 255) << 21);
        p = atomicAdd(&cur_s[d.z >> 8], 1); records[p] = (e + 2) | ((d.z & 255) << 21);
        p = atomicAdd(&cur_s[d.w >> 8], 1); records[p] = (e + 3) | ((d.w & 255) << 21);
    }
}

__global__ __launch_bounds__(256) void f_finalize(int* __restrict__ records,
                                                  const int* __restrict__ boff,
                                                  int2* __restrict__ offcnt) {
    __shared__ int cnt_s[F_NPB];
    __shared__ int cur_s[F_NPB];
    __shared__ int wsum_s[4];
    const int b = blockIdx.x, t = threadIdx.x;
    const int s0 = boff[b];
    const int tot = ((b + 1 < F_NBUK) ? boff[b + 1] : N_EDGES) - s0;
    cnt_s[t] = 0;
    __syncthreads();
    int held[F_MAXPT];
    #pragma unroll
    for (int r = 0; r < F_MAXPT; ++r) {
        const int i = t + r * 256;
        held[r] = (i < tot) ? records[s0 + i] : -1;
        if (held[r] >= 0) atomicAdd(&cnt_s[held[r] >> 21], 1);
    }
    __syncthreads();
    const int lane = t & 63, w = t >> 6;
    const int v = cnt_s[t];
    int incl = v;
    #pragma unroll
    for (int dd = 1; dd < 64; dd <<= 1) {
        int u = __shfl_up(incl, dd, 64);
        if (lane >= dd) incl += u;
    }
    if (lane == 63) wsum_s[w] = incl;
    __syncthreads();
    int wo = 0;
    for (int ww = 0; ww < w; ++ww) wo += wsum_s[ww];
    const int excl = s0 + wo + incl - v;
    cur_s[t] = excl;
    const int gn = b * F_NPB + t;
    if (gn < N_NODES) offcnt[gn] = make_int2(excl, v);
    __syncthreads();
    #pragma unroll
    for (int r = 0; r < F_MAXPT; ++r) {
        if (held[r] >= 0) {
            const int pos = atomicAdd(&cur_s[held[r] >> 21], 1);
            records[pos] = held[r] & 0x1FFFFF;
        }
    }
}

__global__ __launch_bounds__(256) void f_gather(
    const float* __restrict__ node, const float* __restrict__ edge,
    const int* __restrict__ src, const int2* __restrict__ offcnt,
    const int* __restrict__ eid,
    const float* __restrict__ W, const float* __restrict__ bvec,
    const float* __restrict__ eps, float* __restrict__ out)
{
    __shared__ float Ws[D][D + 1];
    __shared__ float bs[D];
    const int t = threadIdx.x;
    for (int i = t; i < D * D; i += 256) Ws[i >> 5][i & 31] = W[i];
    if (t < D) bs[t] = bvec[t];
    __syncthreads();
    const int g = t >> 5;
    const int o = t & 31;
    const int nodeid = blockIdx.x * 8 + g;
    if (nodeid >= N_NODES) return;
    const int2 oc = offcnt[nodeid];
    const int start = oc.x;
    const int n = oc.y;
    float acc = 0.0f;
    for (int c = 0; c < n; c += 32) {
        const int m = min(32, n - c);
        int e_l = 0, s_l = 0;
        if (o < m) {
            e_l = eid[start + c + o];
            s_l = src[e_l];
        }
        for (int j = 0; j < m; j += 16) {
            float ev[16], nv[16];
            #pragma unroll
            for (int u = 0; u < 16; ++u) {
                const int jj = j + u;
                const int ls = (jj < m) ? jj : (m - 1);
                const int e = __shfl(e_l, ls, 32);
                const int s = __shfl(s_l, ls, 32);
                ev[u] = edge[(long long)e * D + o];
                nv[u] = node[(long long)s * D + o];
            }
            #pragma unroll
            for (int u = 0; u < 16; ++u)
                if (j + u < m) acc += fmaxf(ev[u] + nv[u], 0.0f);
        }
    }
    const float scale = 1.0f + eps[0];
    const float h = scale * node[(long long)nodeid * D + o] + acc;
    float r = bs[o];
    #pragma unroll
    for (int kk = 0; kk < D; ++kk) r += __shfl(h, kk, 32) * Ws[o][kk];
    out[(long long)nodeid * D + o] = r;
}

// ---------------------------------------------------------------------

extern "C" void kernel_launch(void* const* d_in, const int* in_sizes, int n_in,
                              void* d_out, int out_size, void* d_ws, size_t ws_size,
                              hipStream_t stream) {
    const float* node = (const float*)d_in[0];
    const float* edge = (const float*)d_in[1];
    const int*   src  = (const int*)d_in[2];
    const int*   dst  = (const int*)d_in[3];
    const float* W    = (const float*)d_in[4];
    const float* b    = (const float*)d_in[5];
    const float* eps  = (const float*)d_in[6];
    float* out = (float*)d_out;

    // Primary layout: msg bf16[E*32] | nodeb bf16[N*32] | cnt[N] | cur[N] |
    //                 offcnt int2[N] | bsum[NB] | boff[NB]  (~110.5 MB)
    const size_t need = (size_t)N_EDGES * D * 2 + (size_t)N_NODES * D * 2
                      + (size_t)N_NODES * 4 * 4 + (size_t)NB * 8 + 1024;

    if (ws_size >= need) {
        unsigned short* msg   = (unsigned short*)d_ws;
        unsigned short* nodeb = msg + (size_t)N_EDGES * D;
        int*  cnt    = (int*)(nodeb + (size_t)N_NODES * D);
        int*  cur    = cnt + N_NODES;
        int2* offcnt = (int2*)(cur + N_NODES);
        int*  bsum   = (int*)(offcnt + N_NODES);
        int*  boff   = bsum + NB;

        hipMemsetAsync(cnt, 0, (size_t)N_NODES * sizeof(int), stream);
        conv_kernel<<<(N_NODES * D / 4) / 256, 256, 0, stream>>>(
            (const float4*)node, (ushort4*)nodeb);
        deg_hist<<<(N_EDGES / 4 + 255) / 256, 256, 0, stream>>>(
            (const int4*)dst, cnt);
        scan_a<<<NB, SCAN_B, 0, stream>>>(cnt, bsum);
        scan_b<<<1, 512, 0, stream>>>(bsum, boff);
        scan_c<<<NB, SCAN_B, 0, stream>>>(cnt, boff, offcnt, cur);
        mat_kernel<<<2048, 256, 0, stream>>>((const float4*)edge,
                                             (const ushort4*)nodeb,
                                             src, dst, cur, (ushort4*)msg);
        reduce_kernel<<<N_NODES / 8, 256, 0, stream>>>(node, msg, offcnt,
                                                       W, b, eps, out);
    } else {
        // R6 fallback (~7.3 MB)
        int*  records = (int*)d_ws;
        int*  bgcnt   = records + N_EDGES;
        int*  gstart  = bgcnt + F_NBUK * F_NCHUNK;
        int*  boff    = gstart + F_NBUK * F_NCHUNK;
        int2* offcnt  = (int2*)(boff + F_NBUK);

        f_hist<<<F_NCHUNK, 256, 0, stream>>>((const int4*)dst, bgcnt);
        f_offsets<<<1, 512, 0, stream>>>(bgcnt, gstart, boff);
        f_scatter<<<F_NCHUNK, 256, 0, stream>>>((const int4*)dst, gstart, records);
        f_finalize<<<F_NBUK, 256, 0, stream>>>(records, boff, offcnt);
        f_gather<<<(N_NODES + 7) / 8, 256, 0, stream>>>(node, edge, src, offcnt,
                                                        records, W, b, eps, out);
    }
}

// Round 8
// 160.994 us; speedup vs baseline: 1.4257x; 1.4257x over previous
//
#include <hip/hip_runtime.h>

constexpr int N_NODES = 100000;
constexpr int N_EDGES = 1600000;
constexpr int D = 32;
constexpr int NPB = 256;                            // nodes per bucket
constexpr int NBUK = (N_NODES + NPB - 1) / NPB;     // 391 buckets
constexpr int NCHUNK = 128;                         // edge chunks (hist/scatter blocks)
constexpr int EPC = N_EDGES / NCHUNK;               // 12500 edges per chunk (exact)
constexpr int MAXPT = 32;                           // finalize: 32*256=8192 >= mean 4096 + 64 sigma

// K1: per-chunk LDS histogram over buckets -> bgcnt[chunk][bucket] (chunk-major).
__global__ __launch_bounds__(256) void hist_kernel(const int4* __restrict__ dst4,
                                                   int* __restrict__ bgcnt) {
    __shared__ int cnt_s[512];
    const int k = blockIdx.x, t = threadIdx.x;
    cnt_s[t] = 0; cnt_s[t + 256] = 0;
    __syncthreads();
    const int base4 = k * (EPC / 4);
    for (int i = t; i < EPC / 4; i += 256) {
        int4 d = dst4[base4 + i];
        atomicAdd(&cnt_s[d.x >> 8], 1);
        atomicAdd(&cnt_s[d.y >> 8], 1);
        atomicAdd(&cnt_s[d.z >> 8], 1);
        atomicAdd(&cnt_s[d.w >> 8], 1);
    }
    __syncthreads();
    for (int b = t; b < NBUK; b += 256) bgcnt[k * NBUK + b] = cnt_s[b];
}

// K2: bucket totals -> exclusive bucket scan (boff) + per-(chunk,bucket) starts
// (gstart, chunk-major). All bgcnt accesses coalesced across the 391 buckets.
__global__ __launch_bounds__(512) void offsets_kernel(const int* __restrict__ bgcnt,
                                                      int* __restrict__ gstart,
                                                      int* __restrict__ boff) {
    __shared__ int part[512];
    const int t = threadIdx.x;
    int tot = 0;
    if (t < NBUK)
        for (int k = 0; k < NCHUNK; ++k) tot += bgcnt[k * NBUK + t];
    part[t] = tot;
    __syncthreads();
    for (int d = 1; d < 512; d <<= 1) {
        int u = (t >= d) ? part[t - d] : 0;
        __syncthreads();
        part[t] += u;
        __syncthreads();
    }
    const int my_off = part[t] - tot;      // exclusive bucket offset
    if (t < NBUK) {
        boff[t] = my_off;
        int run = my_off;
        for (int k = 0; k < NCHUNK; ++k) {
            gstart[k * NBUK + t] = run;
            run += bgcnt[k * NBUK + t];    // L2-hot re-read, coalesced
        }
    }
}

// K3: scatter packed records (e | local<<21) to bucket-major order.
// Each (bucket,chunk) stripe is contiguous and written by exactly one block.
__global__ __launch_bounds__(256) void scatter_kernel(const int4* __restrict__ dst4,
                                                      const int* __restrict__ gstart,
                                                      int* __restrict__ records) {
    __shared__ int cur_s[512];
    const int k = blockIdx.x, t = threadIdx.x;
    for (int b = t; b < 512; b += 256)
        cur_s[b] = (b < NBUK) ? gstart[k * NBUK + b] : 0;
    __syncthreads();
    const int base4 = k * (EPC / 4);
    for (int i = t; i < EPC / 4; i += 256) {
        int4 d = dst4[base4 + i];
        const int e = (base4 + i) * 4;
        int p;
        p = atomicAdd(&cur_s[d.x >> 8], 1); records[p] = e       | ((d.x & 255) << 21);
        p = atomicAdd(&cur_s[d.y >> 8], 1); records[p] = (e + 1) | ((d.y & 255) << 21);
        p = atomicAdd(&cur_s[d.z >> 8], 1); records[p] = (e + 2) | ((d.z & 255) << 21);
        p = atomicAdd(&cur_s[d.w >> 8], 1); records[p] = (e + 3) | ((d.w & 255) << 21);
    }
}

// K4: one block per bucket. Buffer records in registers (static indices),
// LDS hist+scan of 256 local nodes -> offcnt, then in-place rewrite the same
// contiguous region as node-sorted CSR eid (block-exclusive).
__global__ __launch_bounds__(256) void finalize_kernel(int* __restrict__ records,
                                                       const int* __restrict__ boff,
                                                       int2* __restrict__ offcnt) {
    __shared__ int cnt_s[NPB];
    __shared__ int cur_s[NPB];
    __shared__ int wsum_s[4];
    const int b = blockIdx.x, t = threadIdx.x;
    const int s0 = boff[b];
    const int tot = ((b + 1 < NBUK) ? boff[b + 1] : N_EDGES) - s0;
    cnt_s[t] = 0;
    __syncthreads();

    int held[MAXPT];
    #pragma unroll
    for (int r = 0; r < MAXPT; ++r) {
        const int i = t + r * 256;
        held[r] = (i < tot) ? records[s0 + i] : -1;
        if (held[r] >= 0) atomicAdd(&cnt_s[held[r] >> 21], 1);
    }
    __syncthreads();

    const int lane = t & 63, w = t >> 6;
    const int v = cnt_s[t];
    int incl = v;
    #pragma unroll
    for (int dd = 1; dd < 64; dd <<= 1) {
        int u = __shfl_up(incl, dd, 64);
        if (lane >= dd) incl += u;
    }
    if (lane == 63) wsum_s[w] = incl;
    __syncthreads();
    int wo = 0;
    for (int ww = 0; ww < w; ++ww) wo += wsum_s[ww];
    const int excl = s0 + wo + incl - v;
    cur_s[t] = excl;
    const int gn = b * NPB + t;
    if (gn < N_NODES) offcnt[gn] = make_int2(excl, v);
    __syncthreads();

    #pragma unroll
    for (int r = 0; r < MAXPT; ++r) {
        if (held[r] >= 0) {
            const int pos = atomicAdd(&cur_s[held[r] >> 21], 1);
            records[pos] = held[r] & 0x1FFFFF;
        }
    }
}

// K5: one node per WAVE (64 lanes = 2 halves x 32 features). Power-of-2 batch
// descent issues exactly `degree` edge-rows + node-rows (no clamp duplicates),
// degree is wave-uniform (no divergence). Halves combine via shfl_xor(32).
#define GINE_BATCH(K)                                                      \
    {                                                                      \
        float ev[K], nv[K];                                                \
        _Pragma("unroll")                                                  \
        for (int u = 0; u < K; ++u) {                                      \
            const int idx = j + 2 * u + half;                              \
            const int e = __shfl(e_l, idx, 64);                            \
            const int s = __shfl(s_l, idx, 64);                            \
            ev[u] = edge[(long long)e * D + o];                            \
            nv[u] = node[(long long)s * D + o];                            \
        }                                                                  \
        _Pragma("unroll")                                                  \
        for (int u = 0; u < K; ++u)                                        \
            acc += fmaxf(ev[u] + nv[u], 0.0f);                             \
        j += 2 * K;                                                        \
    }

__global__ __launch_bounds__(256) void gather_node_kernel(
    const float* __restrict__ node, const float* __restrict__ edge,
    const int* __restrict__ src, const int2* __restrict__ offcnt,
    const int* __restrict__ eid,
    const float* __restrict__ W, const float* __restrict__ bvec,
    const float* __restrict__ eps, float* __restrict__ out)
{
    __shared__ float Ws[D][D + 1];
    __shared__ float bs[D];
    const int t = threadIdx.x;
    for (int i = t; i < D * D; i += 256) Ws[i >> 5][i & 31] = W[i];
    if (t < D) bs[t] = bvec[t];
    __syncthreads();

    const int wv = t >> 6;                 // wave in block (0..3)
    const int l = t & 63;
    const int o = l & 31;                  // feature
    const int half = l >> 5;               // 0/1: which edge parity this lane covers
    const int nodeid = blockIdx.x * 4 + wv;    // 25000*4 == N_NODES exact

    const int2 oc = offcnt[nodeid];
    const int start = oc.x;
    const int n = oc.y;
    float acc = 0.0f;

    for (int c = 0; c < n; c += 64) {
        const int m = min(64, n - c);      // wave-uniform
        int e_l = 0, s_l = 0;
        if (l < m) {
            e_l = eid[start + c + l];      // coalesced 64-wide
            s_l = src[e_l];                // 4B gather, L2/L3-hot
        }
        int j = 0;
        while (j + 16 <= m) GINE_BATCH(8)      // 16 edges: 8 ev + 8 nv per lane
        if (j + 8 <= m) GINE_BATCH(4)
        if (j + 4 <= m) GINE_BATCH(2)
        if (j + 2 <= m) GINE_BATCH(1)
        if (j < m) {                           // single leftover edge: half 0 only
            const int e = __shfl(e_l, j, 64);
            const int s = __shfl(s_l, j, 64);
            float v0 = 0.0f;
            if (half == 0)
                v0 = fmaxf(edge[(long long)e * D + o] + node[(long long)s * D + o], 0.0f);
            acc += v0;
        }
    }

    acc += __shfl_xor(acc, 32);            // combine the two halves (wave64)

    const float scale = 1.0f + eps[0];
    const float h = scale * node[(long long)nodeid * D + o] + acc;

    float r = bs[o];
    #pragma unroll
    for (int k = 0; k < D; ++k) r += __shfl(h, k, 32) * Ws[o][k];
    if (half == 0) out[(long long)nodeid * D + o] = r;   // 128B coalesced row
}

extern "C" void kernel_launch(void* const* d_in, const int* in_sizes, int n_in,
                              void* d_out, int out_size, void* d_ws, size_t ws_size,
                              hipStream_t stream) {
    const float* node = (const float*)d_in[0];
    const float* edge = (const float*)d_in[1];
    const int*   src  = (const int*)d_in[2];
    const int*   dst  = (const int*)d_in[3];
    const float* W    = (const float*)d_in[4];
    const float* b    = (const float*)d_in[5];
    const float* eps  = (const float*)d_in[6];
    float* out = (float*)d_out;

    // Workspace: records[E] | bgcnt[NCHUNK*NBUK] | gstart[NCHUNK*NBUK] |
    //            boff[NBUK] | offcnt(int2)[N]   (~8 MB total)
    int*  records = (int*)d_ws;
    int*  bgcnt   = records + N_EDGES;
    int*  gstart  = bgcnt + NCHUNK * NBUK;
    int*  boff    = gstart + NCHUNK * NBUK;
    int2* offcnt  = (int2*)(boff + NBUK);

    hist_kernel<<<NCHUNK, 256, 0, stream>>>((const int4*)dst, bgcnt);
    offsets_kernel<<<1, 512, 0, stream>>>(bgcnt, gstart, boff);
    scatter_kernel<<<NCHUNK, 256, 0, stream>>>((const int4*)dst, gstart, records);
    finalize_kernel<<<NBUK, 256, 0, stream>>>(records, boff, offcnt);

    gather_node_kernel<<<N_NODES / 4, 256, 0, stream>>>(node, edge, src, offcnt,
                                                        records, W, b, eps, out);
}